// Round 1
// 146.633 us; speedup vs baseline: 1.0302x; 1.0302x over previous
//
#include <hip/hip_runtime.h>
#include <cmath>

#define A_CNT 196416
#define C_CNT 90
#define QUADS (A_CNT / 4)            // 49104 quads (4 anchors = 1440 B each)
#define QITERS (QUADS / 8)           // 6138 wave-iterations (8 quads per wave)
#define TOPK 100u
#define CAPB 2048
#define NB_RED 1536                  // 6144 waves -> exactly 1 quad-iter per wave
#define NB_GAT 192

// ws layout (bytes):
//   [0, 785664)          keys[A]   (uint32 monotonic score keys; 0 = below threshold)
//   [785664, 789760)     hist1[1024] (coarse: idx 0 = zero-key, 1..565 = top16-0x3D4B)
//   [789760, 789824)     ctrl[16]: 0=binB(top16) 1=G 5=candA_cnt 6=candB_cnt 8=doneR 9=doneG
//   [789824, 790336)     candA[128]  (keys strictly above binB; count = G < 100)
//   [790336, 798528)     candB[2048] (keys with top16 == binB)
#define OFF_HIST1 785664u
#define OFF_CTRL  789760u
#define OFF_CANDA 789824u
#define OFF_CANDB 790336u

#define AGENT_LD(p)    __hip_atomic_load((p), __ATOMIC_RELAXED, __HIP_MEMORY_SCOPE_AGENT)
#define AGENT_ST(p, v) __hip_atomic_store((p), (v), __ATOMIC_RELAXED, __HIP_MEMORY_SCOPE_AGENT)

// Kernel 1: 8 lanes cooperate on one QUAD (4 anchors, 90 float4 = 1440 B).
// MLP fix (R6): all 12 float4 loads per lane are issued into distinct registers
// BEFORE any reduction — the old 6-load/pair structure at VGPR_Count=16 had the
// allocator recycling load registers (s_waitcnt between loads, ~2 in flight),
// leaving HBM at 776 GB/s. Each wave does exactly one quad-iter, so the whole
// grid floods memory at launch. Fused tail unchanged: the LAST block (done
// counter) runs the 1024-bin suffix-scan select and publishes binB/G in ctrl.
// Visibility: every thread's hist1 atomics complete (vmcnt) at the
// __syncthreads before t0's done-increment; the last block reads hist1 with
// agent-scope loads (G16).
__global__ __launch_bounds__(256, 4) void k_reduce(const float* __restrict__ cls,
                                                   unsigned* __restrict__ keys,
                                                   unsigned* __restrict__ hist1,
                                                   unsigned* __restrict__ ctrl) {
    __shared__ unsigned lhist[576];
    __shared__ unsigned sdata[256];
    __shared__ unsigned sbin[2];
    __shared__ int sflag;
    const int t = threadIdx.x;
    for (int j = t; j < 576; j += 256) lhist[j] = 0u;
    __syncthreads();

    const int lane = t & 63;
    const int g = lane >> 3, s = lane & 7;
    const int wid = blockIdx.x * 4 + (t >> 6);
    const float4* __restrict__ cls4 = (const float4*)cls;

    if (wid < QITERS) {
        const int q = wid * 8 + g;                   // quad index < 49104
        const float4* __restrict__ r4 = cls4 + (size_t)q * 90;
        // Phase 1: issue ALL loads (distinct, statically-indexed registers).
        float4 v[12];
#pragma unroll
        for (int i = 0; i < 12; ++i) {
            const int j = s + 8 * i;                 // only i=11 can exceed 89
            v[i] = r4[(j < 90) ? j : 89];            // clamp dup = same line; masked below
        }
        // Phase 2: reduce. Quad anchors a0..a3 at float offsets 0/90/180/270;
        // straddle chunks: j=22 (88,89|90,91) and j=67 (268,269|270,271).
        float m0 = -INFINITY, m1 = -INFINITY, m2 = -INFINITY, m3 = -INFINITY;
#pragma unroll
        for (int i = 0; i < 12; ++i) {
            const int j = s + 8 * i;
            const float4 vv = v[i];
            const float a01 = fmaxf(vv.x, vv.y), a23 = fmaxf(vv.z, vv.w);
            const float all = fmaxf(a01, a23);
            if (j < 22)       m0 = fmaxf(m0, all);
            else if (j == 22) { m0 = fmaxf(m0, a01); m1 = fmaxf(m1, a23); }
            else if (j < 45)  m1 = fmaxf(m1, all);
            else if (j < 67)  m2 = fmaxf(m2, all);
            else if (j == 67) { m2 = fmaxf(m2, a01); m3 = fmaxf(m3, a23); }
            else if (j < 90)  m3 = fmaxf(m3, all);
        }
#pragma unroll
        for (int d = 1; d < 8; d <<= 1) {            // reduce across the 8-lane group
            m0 = fmaxf(m0, __shfl_xor(m0, d));
            m1 = fmaxf(m1, __shfl_xor(m1, d));
            m2 = fmaxf(m2, __shfl_xor(m2, d));
            m3 = fmaxf(m3, __shfl_xor(m3, d));
        }
        if (s == 0) {
            float p0 = 1.0f / (1.0f + expf(-m0));    // sigmoid(max) == max(sigmoid)
            float p1 = 1.0f / (1.0f + expf(-m1));
            float p2 = 1.0f / (1.0f + expf(-m2));
            float p3 = 1.0f / (1.0f + expf(-m3));
            unsigned k0 = (p0 > 0.05f) ? __float_as_uint(p0) : 0u;
            unsigned k1 = (p1 > 0.05f) ? __float_as_uint(p1) : 0u;
            unsigned k2 = (p2 > 0.05f) ? __float_as_uint(p2) : 0u;
            unsigned k3 = (p3 > 0.05f) ? __float_as_uint(p3) : 0u;
            *(uint4*)(keys + 4 * (size_t)q) = make_uint4(k0, k1, k2, k3);
            unsigned h0 = k0 ? (min(k0 >> 16, 0x3F80u) - 0x3D4Bu) : 0u;  // 0=zeros, 1..565
            unsigned h1 = k1 ? (min(k1 >> 16, 0x3F80u) - 0x3D4Bu) : 0u;
            unsigned h2 = k2 ? (min(k2 >> 16, 0x3F80u) - 0x3D4Bu) : 0u;
            unsigned h3 = k3 ? (min(k3 >> 16, 0x3F80u) - 0x3D4Bu) : 0u;
            atomicAdd(&lhist[h0], 1u);
            atomicAdd(&lhist[h1], 1u);
            atomicAdd(&lhist[h2], 1u);
            atomicAdd(&lhist[h3], 1u);
        }
    }
    __syncthreads();
    for (int j = t; j < 576; j += 256) {
        unsigned c = lhist[j];
        if (c) atomicAdd(&hist1[j], c);
    }
    __syncthreads();                                 // drains each thread's atomics (vmcnt)
    if (t == 0) sflag = (atomicAdd(&ctrl[8], 1u) == NB_RED - 1u) ? 1 : 0;
    __syncthreads();
    if (!sflag) return;

    // ---- fused k_scan (last block only; uniform branch, barriers legal) ----
    const unsigned target = TOPK;
    unsigned ssum = 0;
#pragma unroll
    for (int j = 0; j < 4; ++j) ssum += AGENT_LD(&hist1[t * 4 + j]);
    sdata[t] = ssum;
    for (int d = 1; d < 256; d <<= 1) {              // Hillis-Steele inclusive suffix scan
        __syncthreads();
        unsigned add = (t + d < 256) ? sdata[t + d] : 0u;
        __syncthreads();
        sdata[t] += add;
    }
    __syncthreads();
    {
        unsigned mysuf  = sdata[t];
        unsigned nxtsuf = (t < 255) ? sdata[t + 1] : 0u;
        if (nxtsuf < target && mysuf >= target) { sbin[0] = (unsigned)t; sbin[1] = nxtsuf; }
    }
    __syncthreads();
    const unsigned chunkB = sbin[0];
    const unsigned gAbove = sbin[1];
    unsigned v = (t < 4) ? AGENT_LD(&hist1[chunkB * 4 + t]) : 0u;
    sdata[t] = v;
    for (int d = 1; d < 256; d <<= 1) {
        __syncthreads();
        unsigned add = (t + d < 256) ? sdata[t + d] : 0u;
        __syncthreads();
        sdata[t] += add;
    }
    __syncthreads();
    {
        unsigned mysuf  = sdata[t] + gAbove;
        unsigned nxtsuf = ((t < 255) ? sdata[t + 1] : 0u) + gAbove;
        if (nxtsuf < target && mysuf >= target) {
            unsigned bin = chunkB * 4 + (unsigned)t;  // hist index: 0=zeros, 1..565
            ctrl[0] = bin ? (bin + 0x3D4Bu) : 0u;     // true top-16 bits
            ctrl[1] = nxtsuf;                         // G < 100
        }
    }
}

// Kernel 2: gather candidates (one uint4 pass over keys), then the LAST block
// runs the full ranking + argmax + box decode (fused k_final).
// R6: argmax prefetches all 45 float2 of the row into registers before the
// compare chain (old dependent-scatter read was latency-serialized), and
// reg/anc are loaded as float4.
__global__ __launch_bounds__(256) void k_gather(const float* __restrict__ cls,
                                                const float* __restrict__ reg,
                                                const float* __restrict__ anc,
                                                const unsigned* __restrict__ keys,
                                                unsigned* __restrict__ ctrl,
                                                unsigned* __restrict__ candA,
                                                unsigned* __restrict__ candB,
                                                float* __restrict__ out) {
    __shared__ unsigned sAi[128], sAk[128];
    __shared__ unsigned sBi[CAPB], sBk[CAPB];
    __shared__ unsigned sel[TOPK];
    __shared__ int sflag;
    const int t = threadIdx.x;

    const unsigned binB = ctrl[0];                   // prev kernel -> plain load ok
    const int i4 = blockIdx.x * 256 + t;
    if (i4 < A_CNT / 4) {
        uint4 k = ((const uint4*)keys)[i4];
        const unsigned base = (unsigned)(4 * i4);
#pragma unroll
        for (int j = 0; j < 4; ++j) {
            unsigned kk = (j == 0) ? k.x : (j == 1) ? k.y : (j == 2) ? k.z : k.w;
            unsigned t16 = kk >> 16;
            if (t16 > binB) {
                unsigned q = atomicAdd(&ctrl[5], 1u);
                if (q < 128u) AGENT_ST(&candA[q], base + j);
            } else if (t16 == binB) {
                unsigned q = atomicAdd(&ctrl[6], 1u);
                if (q < (unsigned)CAPB) AGENT_ST(&candB[q], base + j);
            }
        }
    }
    __syncthreads();                                 // drains this thread's stores/atomics
    if (t == 0) sflag = (atomicAdd(&ctrl[9], 1u) == (unsigned)NB_GAT - 1u) ? 1 : 0;
    __syncthreads();
    if (!sflag) return;

    // ---- fused k_final (last block only) ----
    const unsigned nA = min(AGENT_LD(&ctrl[5]), 128u);   // exact G < 100
    const unsigned nB = min(AGENT_LD(&ctrl[6]), (unsigned)CAPB);
    const unsigned need = TOPK - nA;                     // >= 1; in-bin count >= need

    if (t < (int)nA) { unsigned i = AGENT_LD(&candA[t]); sAi[t] = i; sAk[t] = keys[i]; }
    for (unsigned e = (unsigned)t; e < nB; e += 256u) {
        unsigned i = AGENT_LD(&candB[e]); sBi[e] = i; sBk[e] = keys[i];
    }
    __syncthreads();

    if (t < (int)nA) {                               // rank strictly-above candidates
        unsigned mi = sAi[t], mk = sAk[t], r = 0;
        for (unsigned j = 0; j < nA; ++j) {
            unsigned ok = sAk[j];
            if (ok > mk || (ok == mk && sAi[j] < mi)) r++;
        }
        sel[r] = mi;
    }
    for (unsigned e = (unsigned)t; e < nB; e += 256u) {  // in-bin: (key desc, idx asc)
        unsigned mi = sBi[e], mk = sBk[e], r = 0;
        for (unsigned j = 0; j < nB; ++j) {
            unsigned ok = sBk[j];
            if (ok > mk || (ok == mk && sBi[j] < mi)) r++;
        }
        if (r < need) sel[nA + r] = mi;
    }
    __syncthreads();

    if (t < (int)TOPK) {
        const unsigned a = sel[t];
        const float2* __restrict__ row = (const float2*)(cls + (size_t)a * C_CNT);
        float2 vr[45];
#pragma unroll
        for (int c = 0; c < 45; ++c) vr[c] = row[c]; // issue all 45 loads up front
        float bv = -INFINITY; int bi = 0;
#pragma unroll
        for (int c = 0; c < 45; ++c) {               // argmax over RAW logits (sigmoid
            if (vr[c].x > bv) { bv = vr[c].x; bi = 2 * c; }      // monotonic; strict > =
            if (vr[c].y > bv) { bv = vr[c].y; bi = 2 * c + 1; }  // first-index semantics)
        }
        float score = __uint_as_float(keys[a]);      // prob bits, or 0.0 if thresholded
        const float4 an = ((const float4*)anc)[a];
        const float4 rg = ((const float4*)reg)[a];
        float wa = an.z - an.x, ha = an.w - an.y;
        float cxa = an.x + 0.5f * wa, cya = an.y + 0.5f * ha;
        float dx = rg.x * 0.1f, dy = rg.y * 0.1f;
        float dw = rg.z * 0.2f, dh = rg.w * 0.2f;
        float cx = cxa + dx * wa, cy = cya + dy * ha;
        float w = expf(dw) * wa, h = expf(dh) * ha;
        out[t * 4 + 0] = fmaxf(cx - 0.5f * w, 0.0f);
        out[t * 4 + 1] = fmaxf(cy - 0.5f * h, 0.0f);
        out[t * 4 + 2] = fminf(cx + 0.5f * w, 1024.0f);
        out[t * 4 + 3] = fminf(cy + 0.5f * h, 1024.0f);
        out[400 + t] = score;
        out[500 + t] = (float)bi;
    }
}

extern "C" void kernel_launch(void* const* d_in, const int* in_sizes, int n_in,
                              void* d_out, int out_size, void* d_ws, size_t ws_size,
                              hipStream_t stream) {
    const float* reg = (const float*)d_in[1];
    const float* cls = (const float*)d_in[2];
    const float* anc = (const float*)d_in[3];
    float* out = (float*)d_out;
    char* ws = (char*)d_ws;
    unsigned* keys  = (unsigned*)ws;
    unsigned* hist1 = (unsigned*)(ws + OFF_HIST1);
    unsigned* ctrl  = (unsigned*)(ws + OFF_CTRL);
    unsigned* candA = (unsigned*)(ws + OFF_CANDA);
    unsigned* candB = (unsigned*)(ws + OFF_CANDB);

    // hist1 (4 KB) + ctrl (64 B, incl. done counters) are contiguous.
    hipMemsetAsync(hist1, 0, 4096 + 64, stream);
    k_reduce<<<NB_RED, 256, 0, stream>>>(cls, keys, hist1, ctrl);
    k_gather<<<NB_GAT, 256, 0, stream>>>(cls, reg, anc, keys, ctrl, candA, candB, out);
}

// Round 2
// 133.942 us; speedup vs baseline: 1.1278x; 1.0948x over previous
//
#include <hip/hip_runtime.h>
#include <cmath>

#define A_CNT 196416
#define C_CNT 90
#define QUADS (A_CNT / 4)            // 49104 quads (4 anchors = 1440 B each)
#define QITERS (QUADS / 8)           // 6138 wave-iterations (8 quads per wave-iter)
#define TOPK 100u
#define CAPB 2048
#define NB_RED 512                   // 2 blocks/CU, fully resident, 2048 waves
#define NWAVES 2048                  // grid-stride in wave-iters
#define NB_GAT 192

// ws layout (bytes):
//   [0, 785664)          keys[A]   (uint32 monotonic score keys; 0 = below threshold)
//   [785664, 789760)     hist1[1024] (coarse: idx 0 = zero-key, 1..565 = top16-0x3D4B)
//   [789760, 789824)     ctrl[16]: 0=binB(top16) 1=G 5=candA_cnt 6=candB_cnt 8=doneR 9=doneG
//   [789824, 790336)     candA[128]  (keys strictly above binB; count = G < 100)
//   [790336, 798528)     candB[2048] (keys with top16 == binB)
#define OFF_HIST1 785664u
#define OFF_CTRL  789760u
#define OFF_CANDA 789824u
#define OFF_CANDB 790336u

#define AGENT_LD(p)    __hip_atomic_load((p), __ATOMIC_RELAXED, __HIP_MEMORY_SCOPE_AGENT)
#define AGENT_ST(p, v) __hip_atomic_store((p), (v), __ATOMIC_RELAXED, __HIP_MEMORY_SCOPE_AGENT)

// ---- R7: pinned load batches + rolling double-buffer -----------------------
// R5 (VGPR_Count=16) and R6 both ran at ~1.7 TB/s: the compiler re-fuses the
// load loop into the reduce loop (pressure-minimizing schedule), leaving ~1
// load in flight per wave. sched_barrier(0) after each 12-load batch pins the
// cluster so all 12 global_load_dwordx4 issue before any consumer. 3 iters per
// wave with a 2-deep register pipeline keeps 24 KB/wave outstanding across the
// reduce phases (no __syncthreads between loads and use -> no vmcnt(0) drain).

#define LOADQ(V, qq)                                                        \
    {                                                                       \
        const float4* __restrict__ r4_ = cls4 + (size_t)(qq) * 90;          \
        _Pragma("unroll")                                                   \
        for (int i_ = 0; i_ < 12; ++i_) {                                   \
            const int j_ = s + 8 * i_;                                      \
            V[i_] = r4_[(j_ < 90) ? j_ : 89];  /* clamp dup; masked below */ \
        }                                                                   \
    }                                                                       \
    __builtin_amdgcn_sched_barrier(0);

// Quad anchors a0..a3 at float offsets 0/90/180/270 within the 360-float quad;
// straddle chunks: j=22 (88,89|90,91) and j=67 (268,269|270,271).
#define REDUCE_EMIT(V, qq)                                                  \
    {                                                                       \
        float m0 = -INFINITY, m1 = -INFINITY, m2 = -INFINITY, m3 = -INFINITY; \
        _Pragma("unroll")                                                   \
        for (int i_ = 0; i_ < 12; ++i_) {                                   \
            const int j_ = s + 8 * i_;                                      \
            const float4 vv = V[i_];                                        \
            const float a01 = fmaxf(vv.x, vv.y), a23 = fmaxf(vv.z, vv.w);   \
            const float all = fmaxf(a01, a23);                              \
            if (j_ < 22)       m0 = fmaxf(m0, all);                         \
            else if (j_ == 22) { m0 = fmaxf(m0, a01); m1 = fmaxf(m1, a23); }\
            else if (j_ < 45)  m1 = fmaxf(m1, all);                         \
            else if (j_ < 67)  m2 = fmaxf(m2, all);                         \
            else if (j_ == 67) { m2 = fmaxf(m2, a01); m3 = fmaxf(m3, a23); }\
            else if (j_ < 90)  m3 = fmaxf(m3, all);                         \
        }                                                                   \
        _Pragma("unroll")                                                   \
        for (int d_ = 1; d_ < 8; d_ <<= 1) {                                \
            m0 = fmaxf(m0, __shfl_xor(m0, d_));                             \
            m1 = fmaxf(m1, __shfl_xor(m1, d_));                             \
            m2 = fmaxf(m2, __shfl_xor(m2, d_));                             \
            m3 = fmaxf(m3, __shfl_xor(m3, d_));                             \
        }                                                                   \
        if (s == 0) {                                                       \
            float p0 = 1.0f / (1.0f + expf(-m0));   /* sigmoid(max)==max(sigmoid) */ \
            float p1 = 1.0f / (1.0f + expf(-m1));                           \
            float p2 = 1.0f / (1.0f + expf(-m2));                           \
            float p3 = 1.0f / (1.0f + expf(-m3));                           \
            unsigned k0 = (p0 > 0.05f) ? __float_as_uint(p0) : 0u;          \
            unsigned k1 = (p1 > 0.05f) ? __float_as_uint(p1) : 0u;          \
            unsigned k2 = (p2 > 0.05f) ? __float_as_uint(p2) : 0u;          \
            unsigned k3 = (p3 > 0.05f) ? __float_as_uint(p3) : 0u;          \
            *(uint4*)(keys + 4 * (size_t)(qq)) = make_uint4(k0, k1, k2, k3);\
            unsigned h0 = k0 ? (min(k0 >> 16, 0x3F80u) - 0x3D4Bu) : 0u;     \
            unsigned h1 = k1 ? (min(k1 >> 16, 0x3F80u) - 0x3D4Bu) : 0u;     \
            unsigned h2 = k2 ? (min(k2 >> 16, 0x3F80u) - 0x3D4Bu) : 0u;     \
            unsigned h3 = k3 ? (min(k3 >> 16, 0x3F80u) - 0x3D4Bu) : 0u;     \
            atomicAdd(&lhist[h0], 1u);                                      \
            atomicAdd(&lhist[h1], 1u);                                      \
            atomicAdd(&lhist[h2], 1u);                                      \
            atomicAdd(&lhist[h3], 1u);                                      \
        }                                                                   \
    }

__global__ __launch_bounds__(256, 2) void k_reduce(const float* __restrict__ cls,
                                                   unsigned* __restrict__ keys,
                                                   unsigned* __restrict__ hist1,
                                                   unsigned* __restrict__ ctrl) {
    __shared__ unsigned lhist[576];
    __shared__ unsigned sdata[256];
    __shared__ unsigned sbin[2];
    __shared__ int sflag;
    const int t = threadIdx.x;
    for (int j = t; j < 576; j += 256) lhist[j] = 0u;
    __syncthreads();

    const int lane = t & 63;
    const int g = lane >> 3, s = lane & 7;
    const int w = blockIdx.x * 4 + (t >> 6);     // wave id in [0, 2048)
    const float4* __restrict__ cls4 = (const float4*)cls;

    // wave w owns iters {w, w+2048, w+4096} ∩ [0, 6138) — exact cover of QITERS.
    const int qi0 = w;
    const int qi1 = w + NWAVES;                  // always < 6138
    const int qi2 = w + 2 * NWAVES;
    const bool has2 = (qi2 < QITERS);            // false only for 6 waves
    const int q0 = qi0 * 8 + g;
    const int q1 = qi1 * 8 + g;
    const int q2 = (has2 ? qi2 : qi0) * 8 + g;   // clamped load target; emit guarded

    float4 vA[12], vB[12];
    LOADQ(vA, q0);                               // 12 loads in flight
    LOADQ(vB, q1);                               // 24 loads in flight
    REDUCE_EMIT(vA, q0);                         // waits vmcnt(12); vB stays in flight
    LOADQ(vA, q2);                               // refill while vB lands
    REDUCE_EMIT(vB, q1);
    if (has2) REDUCE_EMIT(vA, q2);

    __syncthreads();
    for (int j = t; j < 576; j += 256) {
        unsigned c = lhist[j];
        if (c) atomicAdd(&hist1[j], c);
    }
    __syncthreads();                             // drains each thread's atomics (vmcnt)
    if (t == 0) sflag = (atomicAdd(&ctrl[8], 1u) == NB_RED - 1u) ? 1 : 0;
    __syncthreads();
    if (!sflag) return;

    // ---- fused k_scan (last block only; uniform branch, barriers legal) ----
    const unsigned target = TOPK;
    unsigned ssum = 0;
#pragma unroll
    for (int j = 0; j < 4; ++j) ssum += AGENT_LD(&hist1[t * 4 + j]);
    sdata[t] = ssum;
    for (int d = 1; d < 256; d <<= 1) {          // Hillis-Steele inclusive suffix scan
        __syncthreads();
        unsigned add = (t + d < 256) ? sdata[t + d] : 0u;
        __syncthreads();
        sdata[t] += add;
    }
    __syncthreads();
    {
        unsigned mysuf  = sdata[t];
        unsigned nxtsuf = (t < 255) ? sdata[t + 1] : 0u;
        if (nxtsuf < target && mysuf >= target) { sbin[0] = (unsigned)t; sbin[1] = nxtsuf; }
    }
    __syncthreads();
    const unsigned chunkB = sbin[0];
    const unsigned gAbove = sbin[1];
    unsigned v = (t < 4) ? AGENT_LD(&hist1[chunkB * 4 + t]) : 0u;
    sdata[t] = v;
    for (int d = 1; d < 256; d <<= 1) {
        __syncthreads();
        unsigned add = (t + d < 256) ? sdata[t + d] : 0u;
        __syncthreads();
        sdata[t] += add;
    }
    __syncthreads();
    {
        unsigned mysuf  = sdata[t] + gAbove;
        unsigned nxtsuf = ((t < 255) ? sdata[t + 1] : 0u) + gAbove;
        if (nxtsuf < target && mysuf >= target) {
            unsigned bin = chunkB * 4 + (unsigned)t;  // hist index: 0=zeros, 1..565
            ctrl[0] = bin ? (bin + 0x3D4Bu) : 0u;     // true top-16 bits
            ctrl[1] = nxtsuf;                         // G < 100
        }
    }
}

// Kernel 2: gather candidates (one uint4 pass over keys), then the LAST block
// runs the full ranking + argmax + box decode (fused k_final).
__global__ __launch_bounds__(256) void k_gather(const float* __restrict__ cls,
                                                const float* __restrict__ reg,
                                                const float* __restrict__ anc,
                                                const unsigned* __restrict__ keys,
                                                unsigned* __restrict__ ctrl,
                                                unsigned* __restrict__ candA,
                                                unsigned* __restrict__ candB,
                                                float* __restrict__ out) {
    __shared__ unsigned sAi[128], sAk[128];
    __shared__ unsigned sBi[CAPB], sBk[CAPB];
    __shared__ unsigned sel[TOPK];
    __shared__ int sflag;
    const int t = threadIdx.x;

    const unsigned binB = ctrl[0];               // prev kernel -> plain load ok
    const int i4 = blockIdx.x * 256 + t;
    if (i4 < A_CNT / 4) {
        uint4 k = ((const uint4*)keys)[i4];
        const unsigned base = (unsigned)(4 * i4);
#pragma unroll
        for (int j = 0; j < 4; ++j) {
            unsigned kk = (j == 0) ? k.x : (j == 1) ? k.y : (j == 2) ? k.z : k.w;
            unsigned t16 = kk >> 16;
            if (t16 > binB) {
                unsigned q = atomicAdd(&ctrl[5], 1u);
                if (q < 128u) AGENT_ST(&candA[q], base + j);
            } else if (t16 == binB) {
                unsigned q = atomicAdd(&ctrl[6], 1u);
                if (q < (unsigned)CAPB) AGENT_ST(&candB[q], base + j);
            }
        }
    }
    __syncthreads();                             // drains this thread's stores/atomics
    if (t == 0) sflag = (atomicAdd(&ctrl[9], 1u) == (unsigned)NB_GAT - 1u) ? 1 : 0;
    __syncthreads();
    if (!sflag) return;

    // ---- fused k_final (last block only) ----
    const unsigned nA = min(AGENT_LD(&ctrl[5]), 128u);   // exact G < 100
    const unsigned nB = min(AGENT_LD(&ctrl[6]), (unsigned)CAPB);
    const unsigned need = TOPK - nA;                     // >= 1; in-bin count >= need

    if (t < (int)nA) { unsigned i = AGENT_LD(&candA[t]); sAi[t] = i; sAk[t] = keys[i]; }
    for (unsigned e = (unsigned)t; e < nB; e += 256u) {
        unsigned i = AGENT_LD(&candB[e]); sBi[e] = i; sBk[e] = keys[i];
    }
    __syncthreads();

    if (t < (int)nA) {                           // rank strictly-above candidates
        unsigned mi = sAi[t], mk = sAk[t], r = 0;
        for (unsigned j = 0; j < nA; ++j) {
            unsigned ok = sAk[j];
            if (ok > mk || (ok == mk && sAi[j] < mi)) r++;
        }
        sel[r] = mi;
    }
    for (unsigned e = (unsigned)t; e < nB; e += 256u) {  // in-bin: (key desc, idx asc)
        unsigned mi = sBi[e], mk = sBk[e], r = 0;
        for (unsigned j = 0; j < nB; ++j) {
            unsigned ok = sBk[j];
            if (ok > mk || (ok == mk && sBi[j] < mi)) r++;
        }
        if (r < need) sel[nA + r] = mi;
    }
    __syncthreads();

    if (t < (int)TOPK) {
        const unsigned a = sel[t];
        const float2* __restrict__ row = (const float2*)(cls + (size_t)a * C_CNT);
        float2 vr[45];
#pragma unroll
        for (int c = 0; c < 45; ++c) vr[c] = row[c]; // issue all 45 loads up front
        float bv = -INFINITY; int bi = 0;
#pragma unroll
        for (int c = 0; c < 45; ++c) {               // argmax over RAW logits (sigmoid
            if (vr[c].x > bv) { bv = vr[c].x; bi = 2 * c; }      // monotonic; strict > =
            if (vr[c].y > bv) { bv = vr[c].y; bi = 2 * c + 1; }  // first-index semantics)
        }
        float score = __uint_as_float(keys[a]);      // prob bits, or 0.0 if thresholded
        const float4 an = ((const float4*)anc)[a];
        const float4 rg = ((const float4*)reg)[a];
        float wa = an.z - an.x, ha = an.w - an.y;
        float cxa = an.x + 0.5f * wa, cya = an.y + 0.5f * ha;
        float dx = rg.x * 0.1f, dy = rg.y * 0.1f;
        float dw = rg.z * 0.2f, dh = rg.w * 0.2f;
        float cx = cxa + dx * wa, cy = cya + dy * ha;
        float w = expf(dw) * wa, h = expf(dh) * ha;
        out[t * 4 + 0] = fmaxf(cx - 0.5f * w, 0.0f);
        out[t * 4 + 1] = fmaxf(cy - 0.5f * h, 0.0f);
        out[t * 4 + 2] = fminf(cx + 0.5f * w, 1024.0f);
        out[t * 4 + 3] = fminf(cy + 0.5f * h, 1024.0f);
        out[400 + t] = score;
        out[500 + t] = (float)bi;
    }
}

extern "C" void kernel_launch(void* const* d_in, const int* in_sizes, int n_in,
                              void* d_out, int out_size, void* d_ws, size_t ws_size,
                              hipStream_t stream) {
    const float* reg = (const float*)d_in[1];
    const float* cls = (const float*)d_in[2];
    const float* anc = (const float*)d_in[3];
    float* out = (float*)d_out;
    char* ws = (char*)d_ws;
    unsigned* keys  = (unsigned*)ws;
    unsigned* hist1 = (unsigned*)(ws + OFF_HIST1);
    unsigned* ctrl  = (unsigned*)(ws + OFF_CTRL);
    unsigned* candA = (unsigned*)(ws + OFF_CANDA);
    unsigned* candB = (unsigned*)(ws + OFF_CANDB);

    // hist1 (4 KB) + ctrl (64 B, incl. done counters) are contiguous.
    hipMemsetAsync(hist1, 0, 4096 + 64, stream);
    k_reduce<<<NB_RED, 256, 0, stream>>>(cls, keys, hist1, ctrl);
    k_gather<<<NB_GAT, 256, 0, stream>>>(cls, reg, anc, keys, ctrl, candA, candB, out);
}